// Round 2
// baseline (589.150 us; speedup 1.0000x reference)
//
#include <hip/hip_runtime.h>
#include <math.h>

#pragma clang fp contract(off)

#define NB 128
#define NA 8732
#define NC 21
#define TOPK 200
#define BCAP 256
#define CONF_T 0.01
#define NMS_T 0.045

// ---------------------------------------------------------------------------
// masked softmax score, f64 (matches a float64 numpy reference's decisions)
// ---------------------------------------------------------------------------
template <bool USE_WS>
__device__ __forceinline__ double score_masked(const float* __restrict__ conf,
                                               const float* __restrict__ maxv,
                                               const double* __restrict__ denom,
                                               int b, int i, int c) {
  size_t gi = (size_t)b * NA + i;
  double s;
  if (USE_WS) {
    s = exp((double)conf[gi * NC + c] - (double)maxv[gi]) / denom[gi];
  } else {
    const float* row = conf + gi * NC;
    float mx = row[0];
    for (int k = 1; k < NC; ++k) mx = fmaxf(mx, row[k]);
    double d = 0.0;
    for (int k = 0; k < NC; ++k) d += exp((double)row[k] - (double)mx);
    s = exp((double)row[c] - (double)mx) / d;
  }
  return (s > CONF_T) ? s : 0.0;
}

// ---------------------------------------------------------------------------
// kernel 1: per-(b,n) row max (f32) + f64 softmax denominator
// ---------------------------------------------------------------------------
__global__ void k_pre(const float* __restrict__ conf, float* __restrict__ maxv,
                      double* __restrict__ denom) {
  int g = blockIdx.x * blockDim.x + threadIdx.x;
  if (g >= NB * NA) return;
  const float* row = conf + (size_t)g * NC;
  float v[NC];
#pragma unroll
  for (int c = 0; c < NC; ++c) v[c] = row[c];
  float mx = v[0];
#pragma unroll
  for (int c = 1; c < NC; ++c) mx = fmaxf(mx, v[c]);
  double s = 0.0;
#pragma unroll
  for (int c = 0; c < NC; ++c) s += exp((double)v[c] - (double)mx);
  maxv[g] = mx;
  denom[g] = s;
}

// "a comes before b": score desc, index asc (jax.lax.top_k / stable-sort rule)
__device__ __forceinline__ bool entBefore(double sa, int ia, double sb, int ib) {
  return (sa > sb) || (sa == sb && ia < ib);
}

// ---------------------------------------------------------------------------
// kernel 2: one 256-thread block per (b, c)
// ---------------------------------------------------------------------------
template <bool USE_WS>
__global__ __launch_bounds__(256) void k_main(const float* __restrict__ loc,
                                              const float* __restrict__ conf,
                                              const float* __restrict__ anchors,
                                              const float* __restrict__ maxv,
                                              const double* __restrict__ denom,
                                              float* __restrict__ out) {
  int bc = blockIdx.x;
  int b = bc / NC;
  int c = bc % NC;
  int tid = threadIdx.x;
  float* outbase = out + (size_t)bc * TOPK * 5;

  if (c == 0) {  // background class: all zeros
    for (int k = tid; k < TOPK * 5; k += 256) outbase[k] = 0.0f;
    return;
  }

  union U {
    float sf[NA];                      // phase 1: f32 coarse keys (34928 B)
    struct {
      double box[TOPK][4];             // 6400 B, decoded corners (f64)
      double area[TOPK];               // 1600 B
    } p2;
  };
  __shared__ U u;
  __shared__ double ssel[256];
  __shared__ int isel[256];
  __shared__ unsigned hist[256];
  __shared__ double bnds[BCAP];
  __shared__ int bndi[BCAP];
  __shared__ int keepL[256];
  __shared__ unsigned long long wmask[4];
  __shared__ int ctl_k, ctl_cnt, ctl_m;
  __shared__ unsigned ctl_pref;

  // ---- Phase A: masked f64 scores -> f32 coarse keys in LDS ----
  // f32 round-to-nearest is monotone, so f32-key order coarsens f64 order.
  for (int i = tid; i < NA; i += 256) {
    double s = score_masked<USE_WS>(conf, maxv, denom, b, i, c);
    u.sf[i] = (float)s;
  }
  if (tid == 0) { ctl_k = TOPK; ctl_pref = 0u; }
  __syncthreads();

  // ---- Phase B: radix-select the 200th-largest f32 key (4 x 8-bit) ----
  for (int shift = 24; shift >= 0; shift -= 8) {
    hist[tid] = 0u;
    __syncthreads();
    unsigned pref = ctl_pref;
    for (int i = tid; i < NA; i += 256) {
      unsigned key = __float_as_uint(u.sf[i]);
      bool match = (shift == 24) || ((key >> (shift + 8)) == (pref >> (shift + 8)));
      if (match) atomicAdd(&hist[(key >> shift) & 255u], 1u);
    }
    __syncthreads();
    if (tid == 0) {
      int k = ctl_k;
      unsigned cum = 0;
      int d = 255;
      for (; d > 0; --d) {
        unsigned h = hist[d];
        if (cum + h >= (unsigned)k) break;
        cum += h;
      }
      ctl_k = k - (int)cum;                 // rank within bucket d (>=1)
      ctl_pref = pref | ((unsigned)d << shift);
    }
    __syncthreads();
  }
  unsigned Tf = ctl_pref;  // f32 bits of the 200th-largest key
  int kneed = ctl_k;       // how many to take among keys == Tf
  int n1 = TOPK - kneed;   // count of keys strictly greater than Tf

  // ---- Phase C: collect indices ----
  if (tid == 0) { ctl_cnt = 0; ctl_m = 0; }
  __syncthreads();
  for (int i = tid; i < NA; i += 256) {
    unsigned key = __float_as_uint(u.sf[i]);
    if (key > Tf) {
      int p = atomicAdd(&ctl_cnt, 1);
      if (p < 256) isel[p] = i;            // exactly n1 <= 200 by construction
    } else if (key == Tf && Tf != 0u) {
      int q = atomicAdd(&ctl_m, 1);
      if (q < BCAP) bndi[q] = i;
    }
  }
  __syncthreads();

  int zf;  // slots >= zf carry exact-zero scores (output-invisible)
  if (Tf == 0u) {
    // fewer than 200 positive keys: fill with zero-score dummies (keep=false
    // -> zero rows downstream; identity of zero entries never reaches output)
    zf = n1;
    for (int j = n1 + tid; j < TOPK; j += 256) isel[j] = j - n1;
  } else {
    zf = TOPK;
    int m = ctl_m;
    if (m > BCAP) m = BCAP;
    if (tid < m) bnds[tid] = score_masked<USE_WS>(conf, maxv, denom, b, bndi[tid], c);
    __syncthreads();
    if (tid < m) {
      double sq = bnds[tid];
      int iq = bndi[tid];
      int rank = 0;
      for (int r = 0; r < m; ++r)
        if (entBefore(bnds[r], bndi[r], sq, iq)) ++rank;
      if (rank < kneed) isel[n1 + rank] = iq;  // f64-exact boundary resolution
    }
  }
  __syncthreads();

  // ---- exact f64 scores for the 200 selected + sort sentinels ----
  if (tid < TOPK) {
    ssel[tid] = (tid < zf)
                    ? score_masked<USE_WS>(conf, maxv, denom, b, isel[tid], c)
                    : 0.0;
  } else {
    ssel[tid] = -1.0;
    isel[tid] = 0x7fffffff;
  }

  // ---- bitonic sort 256 entries: (score desc, index asc) ----
  for (int kk = 2; kk <= 256; kk <<= 1) {
    for (int j = kk >> 1; j > 0; j >>= 1) {
      __syncthreads();
      int ixj = tid ^ j;
      if (ixj > tid) {
        double s1 = ssel[tid], s2 = ssel[ixj];
        int i1 = isel[tid], i2 = isel[ixj];
        bool up = ((tid & kk) == 0);
        bool sw = up ? entBefore(s2, i2, s1, i1) : entBefore(s1, i1, s2, i2);
        if (sw) {
          ssel[tid] = s2; ssel[ixj] = s1;
          isel[tid] = i2; isel[ixj] = i1;
        }
      }
    }
  }
  __syncthreads();

  // ---- decode the 200 boxes in f64 (np op order), overwriting dead sf ----
  if (tid < TOPK) {
    int ai = isel[tid];
    const float* lp = loc + ((size_t)b * NA + ai) * 4;
    const float* ap = anchors + (size_t)ai * 4;
    double l0 = (double)lp[0], l1 = (double)lp[1];
    double l2 = (double)lp[2], l3 = (double)lp[3];
    double a0 = (double)ap[0], a1 = (double)ap[1];
    double a2 = (double)ap[2], a3 = (double)ap[3];
    double cx = a0 + (l0 * 0.1) * a2;
    double cy = a1 + (l1 * 0.1) * a3;
    double w = a2 * exp(l2 * 0.2);
    double h = a3 * exp(l3 * 0.2);
    double x1 = cx - 0.5 * w, y1 = cy - 0.5 * h;
    double x2 = cx + 0.5 * w, y2 = cy + 0.5 * h;
    u.p2.box[tid][0] = x1; u.p2.box[tid][1] = y1;
    u.p2.box[tid][2] = x2; u.p2.box[tid][3] = y2;
    u.p2.area[tid] = (x2 - x1) * (y2 - y1);
  }
  __syncthreads();

  // ---- greedy NMS: sequential i, one thread per candidate j ----
  // Race-free: keep[i] is only written at iterations i' < i (barrier-ordered);
  // each thread writes only its own keep slot.
  double mx1 = 0, my1 = 0, mx2 = 0, my2 = 0, mar = 0;
  if (tid < TOPK) {
    mx1 = u.p2.box[tid][0]; my1 = u.p2.box[tid][1];
    mx2 = u.p2.box[tid][2]; my2 = u.p2.box[tid][3];
    mar = u.p2.area[tid];
  }
  keepL[tid] = (tid < TOPK) && (ssel[tid] > CONF_T);
  __syncthreads();
  for (int i = 0; i < TOPK; ++i) {
    int ki = keepL[i];
    if (ki && tid > i && tid < TOPK && keepL[tid]) {
      double lx = fmax(u.p2.box[i][0], mx1);
      double ly = fmax(u.p2.box[i][1], my1);
      double rx = fmin(u.p2.box[i][2], mx2);
      double ry = fmin(u.p2.box[i][3], my2);
      double iw = rx - lx; if (iw < 0.0) iw = 0.0;
      double ih = ry - ly; if (ih < 0.0) ih = 0.0;
      double inter = iw * ih;
      double iou = inter / (u.p2.area[i] + mar - inter + 1e-12);
      if (iou > NMS_T) keepL[tid] = 0;
    }
    __syncthreads();
  }

  // ---- pack kept rows to the front (one 64-bit ballot per wave) ----
  bool kj = (tid < TOPK) && (keepL[tid] != 0);
  unsigned long long bal = __ballot((int)kj);
  int wave = tid >> 6, lane = tid & 63;
  if (lane == 0) wmask[wave] = bal;
  __syncthreads();
  int nk = 0;
#pragma unroll
  for (int w = 0; w < 4; ++w) nk += __popcll(wmask[w]);
  if (kj) {
    int pos = 0;
    for (int w = 0; w < wave; ++w) pos += __popcll(wmask[w]);
    pos += __popcll(bal & ((1ull << lane) - 1ull));
    float* o = outbase + (size_t)pos * 5;
    o[0] = (float)ssel[tid];
    o[1] = (float)u.p2.box[tid][0];
    o[2] = (float)u.p2.box[tid][1];
    o[3] = (float)u.p2.box[tid][2];
    o[4] = (float)u.p2.box[tid][3];
  }
  if (tid < TOPK && tid >= nk) {
    float* o = outbase + (size_t)tid * 5;
    o[0] = 0.0f; o[1] = 0.0f; o[2] = 0.0f; o[3] = 0.0f; o[4] = 0.0f;
  }
}

// ---------------------------------------------------------------------------
extern "C" void kernel_launch(void* const* d_in, const int* in_sizes, int n_in,
                              void* d_out, int out_size, void* d_ws, size_t ws_size,
                              hipStream_t stream) {
  const float* loc = (const float*)d_in[0];
  const float* conf = (const float*)d_in[1];
  const float* anchors = (const float*)d_in[2];
  float* out = (float*)d_out;

  const size_t WS_NEED = (size_t)NB * NA * (sizeof(double) + sizeof(float));
  int total = NB * NA;

  if (ws_size >= WS_NEED) {
    double* denom = (double*)d_ws;
    float* maxv = (float*)((char*)d_ws + (size_t)NB * NA * sizeof(double));
    k_pre<<<(total + 255) / 256, 256, 0, stream>>>(conf, maxv, denom);
    k_main<true><<<NB * NC, 256, 0, stream>>>(loc, conf, anchors, maxv, denom, out);
  } else {
    k_main<false><<<NB * NC, 256, 0, stream>>>(loc, conf, anchors, nullptr, nullptr, out);
  }
}

// Round 3
// 538.997 us; speedup vs baseline: 1.0930x; 1.0930x over previous
//
#include <hip/hip_runtime.h>
#include <math.h>

#pragma clang fp contract(off)

#define NB 128
#define NA 8732
#define NC 21
#define TOPK 200
#define BCAP 256
#define CONF_T 0.01
#define NMS_T 0.045
#define NQ (NA / 4)  // 2183 float4 per class-row (8732 % 4 == 0)

// ---------------------------------------------------------------------------
// exact f64 masked softmax score (identical expression everywhere -> the f32
// keys written by k_prep are a monotone coarsening of this exact value)
// ---------------------------------------------------------------------------
__device__ __forceinline__ double exact_score(const float* __restrict__ conf,
                                              const float* __restrict__ maxv,
                                              const double* __restrict__ denom,
                                              int b, int i, int c) {
  size_t gi = (size_t)b * NA + i;
  double s = exp((double)conf[gi * NC + c] - (double)maxv[gi]) / denom[gi];
  return (s > CONF_T) ? s : 0.0;
}

__device__ __forceinline__ bool entBefore(double sa, int ia, double sb, int ib) {
  return (sa > sb) || (sa == sb && ia < ib);
}

// ---------------------------------------------------------------------------
// k_prep: coalesced softmax. Per anchor: 21 f64 exps (shared between denom and
// numerators), writes f32 masked keys transposed [b][c-1][i], plus maxv/denom.
// ---------------------------------------------------------------------------
__global__ __launch_bounds__(256) void k_prep(const float* __restrict__ conf,
                                              float* __restrict__ scores,
                                              float* __restrict__ maxv,
                                              double* __restrict__ denom) {
  int g = blockIdx.x * 256 + threadIdx.x;
  if (g >= NB * NA) return;
  const float* row = conf + (size_t)g * NC;
  float v[NC];
#pragma unroll
  for (int k = 0; k < NC; ++k) v[k] = row[k];
  float mx = v[0];
#pragma unroll
  for (int k = 1; k < NC; ++k) mx = fmaxf(mx, v[k]);
  double e[NC], s = 0.0;
#pragma unroll
  for (int k = 0; k < NC; ++k) {
    e[k] = exp((double)v[k] - (double)mx);
    s += e[k];
  }
  maxv[g] = mx;
  denom[g] = s;
  int b = g / NA, i = g - b * NA;
#pragma unroll
  for (int cc = 1; cc < NC; ++cc) {
    double sc = e[cc] / s;  // same rounding as exact_score's div
    float key = (sc > CONF_T) ? (float)sc : 0.0f;
    scores[((size_t)(b * (NC - 1) + (cc - 1))) * NA + i] = key;
  }
}

// ---------------------------------------------------------------------------
// k_fast: one 256-thread block per (b,c), XCD-swizzled.
// ---------------------------------------------------------------------------
__global__ __launch_bounds__(256) void k_fast(const float* __restrict__ loc,
                                              const float* __restrict__ conf,
                                              const float* __restrict__ anchors,
                                              const float* __restrict__ scores,
                                              const float* __restrict__ maxv,
                                              const double* __restrict__ denom,
                                              float* __restrict__ out) {
  // swizzle: same-b's 21 classes land on ids congruent mod 8 -> same XCD
  int id = blockIdx.x;
  int xcd = id & 7, slot = id >> 3;        // slot 0..335
  int c = slot % NC;
  int b = (slot / NC) * 8 + xcd;           // 0..127, bijective
  int tid = threadIdx.x;
  float* outbase = out + ((size_t)(b * NC + c)) * TOPK * 5;

  if (c == 0) {
    for (int k = tid; k < TOPK * 5; k += 256) outbase[k] = 0.0f;
    return;
  }

  union Ovl {
    unsigned histw[1024];                  // radix phase: per-wave hists
    struct {
      float fbox[TOPK][4];                 // NMS phase: f32 shadow boxes
      float farea[TOPK];
    } s;
  };
  __shared__ Ovl u;
  __shared__ unsigned hist[256];
  __shared__ double ssel[256];
  __shared__ int isel[256];
  __shared__ double bnds[BCAP];
  __shared__ int bndi[BCAP];
  __shared__ double dbox[TOPK][4];
  __shared__ double darea[TOPK];
  __shared__ unsigned supp[TOPK][8];       // word 7 = padding (zero)
  __shared__ unsigned keepw[7];
  __shared__ int ctl_k, ctl_cnt, ctl_m;
  __shared__ unsigned ctl_pref;

  const float* sc = scores + (size_t)(b * (NC - 1) + (c - 1)) * NA;
  const float4* sc4 = (const float4*)sc;

  if (tid == 0) { ctl_k = TOPK; ctl_pref = 0u; ctl_cnt = 0; ctl_m = 0; }

  // ---- radix-select 200th-largest f32 key, scanning global (L2/L3-hot) ----
  int hw = (tid >> 6) * 256;               // per-wave histogram base
  for (int shift = 24; shift >= 0; shift -= 8) {
    for (int t = tid; t < 1024; t += 256) u.histw[t] = 0u;
    __syncthreads();
    unsigned pref = ctl_pref;
    for (int idx = tid; idx < NQ; idx += 256) {
      float4 k4 = sc4[idx];
      unsigned kk[4] = {__float_as_uint(k4.x), __float_as_uint(k4.y),
                        __float_as_uint(k4.z), __float_as_uint(k4.w)};
#pragma unroll
      for (int t = 0; t < 4; ++t) {
        unsigned key = kk[t];
        bool match = (shift == 24) || ((key >> (shift + 8)) == (pref >> (shift + 8)));
        if (match) atomicAdd(&u.histw[hw + ((key >> shift) & 255u)], 1u);
      }
    }
    __syncthreads();
    hist[tid] = u.histw[tid] + u.histw[256 + tid] + u.histw[512 + tid] + u.histw[768 + tid];
    __syncthreads();
    if (tid == 0) {
      int k = ctl_k;
      unsigned cum = 0;
      int d = 255;
      for (; d > 0; --d) {
        unsigned h = hist[d];
        if (cum + h >= (unsigned)k) break;
        cum += h;
      }
      ctl_k = k - (int)cum;
      ctl_pref = pref | ((unsigned)d << shift);
    }
    __syncthreads();
  }
  unsigned Tf = ctl_pref;
  int kneed = ctl_k;
  int n1 = TOPK - kneed;  // count of keys strictly greater than Tf

  // ---- collect indices (strictly greater + boundary == Tf) ----
  for (int idx = tid; idx < NQ; idx += 256) {
    float4 k4 = sc4[idx];
    unsigned kk[4] = {__float_as_uint(k4.x), __float_as_uint(k4.y),
                      __float_as_uint(k4.z), __float_as_uint(k4.w)};
#pragma unroll
    for (int t = 0; t < 4; ++t) {
      unsigned key = kk[t];
      int i = idx * 4 + t;
      if (key > Tf) {
        int p = atomicAdd(&ctl_cnt, 1);
        if (p < 256) isel[p] = i;
      } else if (key == Tf && Tf != 0u) {
        int q = atomicAdd(&ctl_m, 1);
        if (q < BCAP) bndi[q] = i;
      }
    }
  }
  __syncthreads();

  int zf;  // slots >= zf are zero-score dummies (output-invisible)
  if (Tf == 0u) {
    zf = n1;
    for (int j = n1 + tid; j < TOPK; j += 256) isel[j] = j - n1;
    __syncthreads();
  } else {
    zf = TOPK;
    int m = ctl_m;
    if (m > BCAP) m = BCAP;
    if (tid < m) bnds[tid] = exact_score(conf, maxv, denom, b, bndi[tid], c);
    __syncthreads();
    if (tid < m) {
      double sq = bnds[tid];
      int iq = bndi[tid];
      int rank = 0;
      for (int r = 0; r < m; ++r)
        if (entBefore(bnds[r], bndi[r], sq, iq)) ++rank;
      if (rank < kneed) isel[n1 + rank] = iq;  // exact-f64 boundary resolution
    }
    __syncthreads();
  }

  // ---- exact f64 scores for the 200 selected + sort sentinels ----
  if (tid < TOPK) {
    ssel[tid] = (tid < zf) ? exact_score(conf, maxv, denom, b, isel[tid], c) : 0.0;
  } else {
    ssel[tid] = -1.0;
    isel[tid] = 0x7fffffff;
  }

  // ---- bitonic sort 256: (score desc, index asc) ----
  for (int kk = 2; kk <= 256; kk <<= 1) {
    for (int j = kk >> 1; j > 0; j >>= 1) {
      __syncthreads();
      int ixj = tid ^ j;
      if (ixj > tid) {
        double s1 = ssel[tid], s2 = ssel[ixj];
        int i1 = isel[tid], i2 = isel[ixj];
        bool up = ((tid & kk) == 0);
        bool sw = up ? entBefore(s2, i2, s1, i1) : entBefore(s1, i1, s2, i2);
        if (sw) {
          ssel[tid] = s2; ssel[ixj] = s1;
          isel[tid] = i2; isel[ixj] = i1;
        }
      }
    }
  }
  __syncthreads();

  // ---- decode boxes in f64 + f32 shadow copies ----
  if (tid < TOPK) {
    int ai = isel[tid];
    const float* lp = loc + ((size_t)b * NA + ai) * 4;
    const float* ap = anchors + (size_t)ai * 4;
    double l0 = (double)lp[0], l1 = (double)lp[1];
    double l2 = (double)lp[2], l3 = (double)lp[3];
    double a0 = (double)ap[0], a1 = (double)ap[1];
    double a2 = (double)ap[2], a3 = (double)ap[3];
    double cx = a0 + (l0 * 0.1) * a2;
    double cy = a1 + (l1 * 0.1) * a3;
    double w = a2 * exp(l2 * 0.2);
    double h = a3 * exp(l3 * 0.2);
    double x1 = cx - 0.5 * w, y1 = cy - 0.5 * h;
    double x2 = cx + 0.5 * w, y2 = cy + 0.5 * h;
    dbox[tid][0] = x1; dbox[tid][1] = y1; dbox[tid][2] = x2; dbox[tid][3] = y2;
    double ar = (x2 - x1) * (y2 - y1);
    darea[tid] = ar;
    u.s.fbox[tid][0] = (float)x1; u.s.fbox[tid][1] = (float)y1;
    u.s.fbox[tid][2] = (float)x2; u.s.fbox[tid][3] = (float)y2;
    u.s.farea[tid] = (float)ar;
  }
  __syncthreads();

  // ---- suppression bitmask: f32 IoU fast path, f64 recheck in guard band ----
  for (int T = tid; T < TOPK * 7; T += 256) {
    int i = T / 7, w = T - i * 7;
    float ax1 = u.s.fbox[i][0], ay1 = u.s.fbox[i][1];
    float ax2 = u.s.fbox[i][2], ay2 = u.s.fbox[i][3];
    float aar = u.s.farea[i];
    unsigned bits = 0u;
    int j0 = w * 32;
    int j1 = j0 + 32;
    if (j1 > TOPK) j1 = TOPK;
    int js = (j0 > i + 1) ? j0 : i + 1;
    for (int j = js; j < j1; ++j) {
      float lx = fmaxf(ax1, u.s.fbox[j][0]);
      float ly = fmaxf(ay1, u.s.fbox[j][1]);
      float rx = fminf(ax2, u.s.fbox[j][2]);
      float ry = fminf(ay2, u.s.fbox[j][3]);
      float iw = rx - lx; iw = iw > 0.0f ? iw : 0.0f;
      float ih = ry - ly; ih = ih > 0.0f ? ih : 0.0f;
      float inter = iw * ih;
      float io = inter / (aar + u.s.farea[j] - inter + 1e-12f);
      bool sup;
      if (io > 0.040f && io < 0.050f) {  // guard band: decide exactly in f64
        double dlx = fmax(dbox[i][0], dbox[j][0]);
        double dly = fmax(dbox[i][1], dbox[j][1]);
        double drx = fmin(dbox[i][2], dbox[j][2]);
        double dry = fmin(dbox[i][3], dbox[j][3]);
        double diw = drx - dlx; if (diw < 0.0) diw = 0.0;
        double dih = dry - dly; if (dih < 0.0) dih = 0.0;
        double dint = diw * dih;
        double dio = dint / (darea[i] + darea[j] - dint + 1e-12);
        sup = dio > NMS_T;
      } else {
        sup = io > 0.045f;
      }
      if (sup) bits |= 1u << (j - j0);
    }
    supp[i][w] = bits;
  }
  for (int i = tid; i < TOPK; i += 256) supp[i][7] = 0u;
  __syncthreads();

  // ---- greedy NMS on wave 0: keep bits in registers, prefetched rows ----
  if (tid < 64) {
    int l = tid;
    unsigned kr = 0u;
#pragma unroll
    for (int q = 0; q < 4; ++q) {
      int j = l + 64 * q;
      if (j < TOPK && ssel[j] > CONF_T) kr |= 1u << q;
    }
    int base = l >> 5;  // 0 or 1
    unsigned r0 = supp[0][base], r1 = supp[0][base + 2];
    unsigned r2 = supp[0][base + 4], r3 = supp[0][base + 6];
    for (int i = 0; i < TOPK; ++i) {
      int ip = (i + 1 < TOPK) ? i + 1 : i;
      unsigned n0 = supp[ip][base], n1w = supp[ip][base + 2];
      unsigned n2 = supp[ip][base + 4], n3 = supp[ip][base + 6];
      unsigned krow = (unsigned)__shfl((int)kr, i & 63);
      if ((krow >> (i >> 6)) & 1u) {
        unsigned bm = 1u << (l & 31);
        if (r0 & bm) kr &= ~1u;
        if (r1 & bm) kr &= ~2u;
        if (r2 & bm) kr &= ~4u;
        if (r3 & bm) kr &= ~8u;
      }
      r0 = n0; r1 = n1w; r2 = n2; r3 = n3;
    }
#pragma unroll
    for (int q = 0; q < 4; ++q) {
      unsigned long long bal = __ballot((int)((kr >> q) & 1u));
      if (l == 0) {
        keepw[2 * q] = (unsigned)bal;
        if (2 * q + 1 < 7) keepw[2 * q + 1] = (unsigned)(bal >> 32);
      }
    }
  }
  __syncthreads();

  // ---- pack kept rows to the front, zero-fill the rest ----
  int nk = 0;
#pragma unroll
  for (int w = 0; w < 7; ++w) nk += __popc(keepw[w]);
  if (tid < TOPK) {
    int j = tid;
    bool kept = (keepw[j >> 5] >> (j & 31)) & 1u;
    if (kept) {
      int pos = 0;
      for (int w = 0; w < (j >> 5); ++w) pos += __popc(keepw[w]);
      pos += __popc(keepw[j >> 5] & ((1u << (j & 31)) - 1u));
      float* o = outbase + (size_t)pos * 5;
      o[0] = (float)ssel[j];
      o[1] = (float)dbox[j][0];
      o[2] = (float)dbox[j][1];
      o[3] = (float)dbox[j][2];
      o[4] = (float)dbox[j][3];
    }
    if (j >= nk) {
      float* o = outbase + (size_t)j * 5;
      o[0] = 0.0f; o[1] = 0.0f; o[2] = 0.0f; o[3] = 0.0f; o[4] = 0.0f;
    }
  }
}

// ===========================================================================
// Fallback path (R2-proven) — used only if ws_size is too small for fast path
// ===========================================================================
template <bool USE_WS>
__device__ __forceinline__ double score_masked(const float* __restrict__ conf,
                                               const float* __restrict__ maxv,
                                               const double* __restrict__ denom,
                                               int b, int i, int c) {
  size_t gi = (size_t)b * NA + i;
  double s;
  if (USE_WS) {
    s = exp((double)conf[gi * NC + c] - (double)maxv[gi]) / denom[gi];
  } else {
    const float* row = conf + gi * NC;
    float mx = row[0];
    for (int k = 1; k < NC; ++k) mx = fmaxf(mx, row[k]);
    double d = 0.0;
    for (int k = 0; k < NC; ++k) d += exp((double)row[k] - (double)mx);
    s = exp((double)row[c] - (double)mx) / d;
  }
  return (s > CONF_T) ? s : 0.0;
}

__global__ void k_pre(const float* __restrict__ conf, float* __restrict__ maxv,
                      double* __restrict__ denom) {
  int g = blockIdx.x * blockDim.x + threadIdx.x;
  if (g >= NB * NA) return;
  const float* row = conf + (size_t)g * NC;
  float mx = row[0];
  for (int c = 1; c < NC; ++c) mx = fmaxf(mx, row[c]);
  double s = 0.0;
  for (int c = 0; c < NC; ++c) s += exp((double)row[c] - (double)mx);
  maxv[g] = mx;
  denom[g] = s;
}

template <bool USE_WS>
__global__ __launch_bounds__(256) void k_main(const float* __restrict__ loc,
                                              const float* __restrict__ conf,
                                              const float* __restrict__ anchors,
                                              const float* __restrict__ maxv,
                                              const double* __restrict__ denom,
                                              float* __restrict__ out) {
  int bc = blockIdx.x;
  int b = bc / NC;
  int c = bc % NC;
  int tid = threadIdx.x;
  float* outbase = out + (size_t)bc * TOPK * 5;
  if (c == 0) {
    for (int k = tid; k < TOPK * 5; k += 256) outbase[k] = 0.0f;
    return;
  }
  union U {
    float sf[NA];
    struct {
      double box[TOPK][4];
      double area[TOPK];
    } p2;
  };
  __shared__ U u;
  __shared__ double ssel[256];
  __shared__ int isel[256];
  __shared__ unsigned hist[256];
  __shared__ double bnds[BCAP];
  __shared__ int bndi[BCAP];
  __shared__ int keepL[256];
  __shared__ unsigned long long wmask[4];
  __shared__ int ctl_k, ctl_cnt, ctl_m;
  __shared__ unsigned ctl_pref;

  for (int i = tid; i < NA; i += 256) {
    double s = score_masked<USE_WS>(conf, maxv, denom, b, i, c);
    u.sf[i] = (float)s;
  }
  if (tid == 0) { ctl_k = TOPK; ctl_pref = 0u; }
  __syncthreads();
  for (int shift = 24; shift >= 0; shift -= 8) {
    hist[tid] = 0u;
    __syncthreads();
    unsigned pref = ctl_pref;
    for (int i = tid; i < NA; i += 256) {
      unsigned key = __float_as_uint(u.sf[i]);
      bool match = (shift == 24) || ((key >> (shift + 8)) == (pref >> (shift + 8)));
      if (match) atomicAdd(&hist[(key >> shift) & 255u], 1u);
    }
    __syncthreads();
    if (tid == 0) {
      int k = ctl_k;
      unsigned cum = 0;
      int d = 255;
      for (; d > 0; --d) {
        unsigned h = hist[d];
        if (cum + h >= (unsigned)k) break;
        cum += h;
      }
      ctl_k = k - (int)cum;
      ctl_pref = pref | ((unsigned)d << shift);
    }
    __syncthreads();
  }
  unsigned Tf = ctl_pref;
  int kneed = ctl_k;
  int n1 = TOPK - kneed;
  if (tid == 0) { ctl_cnt = 0; ctl_m = 0; }
  __syncthreads();
  for (int i = tid; i < NA; i += 256) {
    unsigned key = __float_as_uint(u.sf[i]);
    if (key > Tf) {
      int p = atomicAdd(&ctl_cnt, 1);
      if (p < 256) isel[p] = i;
    } else if (key == Tf && Tf != 0u) {
      int q = atomicAdd(&ctl_m, 1);
      if (q < BCAP) bndi[q] = i;
    }
  }
  __syncthreads();
  int zf;
  if (Tf == 0u) {
    zf = n1;
    for (int j = n1 + tid; j < TOPK; j += 256) isel[j] = j - n1;
  } else {
    zf = TOPK;
    int m = ctl_m;
    if (m > BCAP) m = BCAP;
    if (tid < m) bnds[tid] = score_masked<USE_WS>(conf, maxv, denom, b, bndi[tid], c);
    __syncthreads();
    if (tid < m) {
      double sq = bnds[tid];
      int iq = bndi[tid];
      int rank = 0;
      for (int r = 0; r < m; ++r)
        if (entBefore(bnds[r], bndi[r], sq, iq)) ++rank;
      if (rank < kneed) isel[n1 + rank] = iq;
    }
  }
  __syncthreads();
  if (tid < TOPK) {
    ssel[tid] = (tid < zf) ? score_masked<USE_WS>(conf, maxv, denom, b, isel[tid], c) : 0.0;
  } else {
    ssel[tid] = -1.0;
    isel[tid] = 0x7fffffff;
  }
  for (int kk = 2; kk <= 256; kk <<= 1) {
    for (int j = kk >> 1; j > 0; j >>= 1) {
      __syncthreads();
      int ixj = tid ^ j;
      if (ixj > tid) {
        double s1 = ssel[tid], s2 = ssel[ixj];
        int i1 = isel[tid], i2 = isel[ixj];
        bool up = ((tid & kk) == 0);
        bool sw = up ? entBefore(s2, i2, s1, i1) : entBefore(s1, i1, s2, i2);
        if (sw) {
          ssel[tid] = s2; ssel[ixj] = s1;
          isel[tid] = i2; isel[ixj] = i1;
        }
      }
    }
  }
  __syncthreads();
  if (tid < TOPK) {
    int ai = isel[tid];
    const float* lp = loc + ((size_t)b * NA + ai) * 4;
    const float* ap = anchors + (size_t)ai * 4;
    double l0 = (double)lp[0], l1 = (double)lp[1];
    double l2 = (double)lp[2], l3 = (double)lp[3];
    double a0 = (double)ap[0], a1 = (double)ap[1];
    double a2 = (double)ap[2], a3 = (double)ap[3];
    double cx = a0 + (l0 * 0.1) * a2;
    double cy = a1 + (l1 * 0.1) * a3;
    double w = a2 * exp(l2 * 0.2);
    double h = a3 * exp(l3 * 0.2);
    double x1 = cx - 0.5 * w, y1 = cy - 0.5 * h;
    double x2 = cx + 0.5 * w, y2 = cy + 0.5 * h;
    u.p2.box[tid][0] = x1; u.p2.box[tid][1] = y1;
    u.p2.box[tid][2] = x2; u.p2.box[tid][3] = y2;
    u.p2.area[tid] = (x2 - x1) * (y2 - y1);
  }
  __syncthreads();
  double mx1 = 0, my1 = 0, mx2 = 0, my2 = 0, mar = 0;
  if (tid < TOPK) {
    mx1 = u.p2.box[tid][0]; my1 = u.p2.box[tid][1];
    mx2 = u.p2.box[tid][2]; my2 = u.p2.box[tid][3];
    mar = u.p2.area[tid];
  }
  keepL[tid] = (tid < TOPK) && (ssel[tid] > CONF_T);
  __syncthreads();
  for (int i = 0; i < TOPK; ++i) {
    int ki = keepL[i];
    if (ki && tid > i && tid < TOPK && keepL[tid]) {
      double lx = fmax(u.p2.box[i][0], mx1);
      double ly = fmax(u.p2.box[i][1], my1);
      double rx = fmin(u.p2.box[i][2], mx2);
      double ry = fmin(u.p2.box[i][3], my2);
      double iw = rx - lx; if (iw < 0.0) iw = 0.0;
      double ih = ry - ly; if (ih < 0.0) ih = 0.0;
      double inter = iw * ih;
      double iou = inter / (u.p2.area[i] + mar - inter + 1e-12);
      if (iou > NMS_T) keepL[tid] = 0;
    }
    __syncthreads();
  }
  bool kj = (tid < TOPK) && (keepL[tid] != 0);
  unsigned long long bal = __ballot((int)kj);
  int wave = tid >> 6, lane = tid & 63;
  if (lane == 0) wmask[wave] = bal;
  __syncthreads();
  int nk = 0;
#pragma unroll
  for (int w = 0; w < 4; ++w) nk += __popcll(wmask[w]);
  if (kj) {
    int pos = 0;
    for (int w = 0; w < wave; ++w) pos += __popcll(wmask[w]);
    pos += __popcll(bal & ((1ull << lane) - 1ull));
    float* o = outbase + (size_t)pos * 5;
    o[0] = (float)ssel[tid];
    o[1] = (float)u.p2.box[tid][0];
    o[2] = (float)u.p2.box[tid][1];
    o[3] = (float)u.p2.box[tid][2];
    o[4] = (float)u.p2.box[tid][3];
  }
  if (tid < TOPK && tid >= nk) {
    float* o = outbase + (size_t)tid * 5;
    o[0] = 0.0f; o[1] = 0.0f; o[2] = 0.0f; o[3] = 0.0f; o[4] = 0.0f;
  }
}

// ---------------------------------------------------------------------------
extern "C" void kernel_launch(void* const* d_in, const int* in_sizes, int n_in,
                              void* d_out, int out_size, void* d_ws, size_t ws_size,
                              hipStream_t stream) {
  const float* loc = (const float*)d_in[0];
  const float* conf = (const float*)d_in[1];
  const float* anchors = (const float*)d_in[2];
  float* out = (float*)d_out;

  const size_t scores_bytes = (size_t)NB * (NC - 1) * NA * sizeof(float);
  const size_t denom_off = scores_bytes;                         // 8-aligned
  const size_t maxv_off = denom_off + (size_t)NB * NA * sizeof(double);
  const size_t WS_FAST = maxv_off + (size_t)NB * NA * sizeof(float);
  const size_t WS_SMALL = (size_t)NB * NA * (sizeof(double) + sizeof(float));
  int total = NB * NA;

  if (ws_size >= WS_FAST) {
    float* scores = (float*)d_ws;
    double* denom = (double*)((char*)d_ws + denom_off);
    float* maxv = (float*)((char*)d_ws + maxv_off);
    k_prep<<<(total + 255) / 256, 256, 0, stream>>>(conf, scores, maxv, denom);
    k_fast<<<NB * NC, 256, 0, stream>>>(loc, conf, anchors, scores, maxv, denom, out);
  } else if (ws_size >= WS_SMALL) {
    double* denom = (double*)d_ws;
    float* maxv = (float*)((char*)d_ws + (size_t)NB * NA * sizeof(double));
    k_pre<<<(total + 255) / 256, 256, 0, stream>>>(conf, maxv, denom);
    k_main<true><<<NB * NC, 256, 0, stream>>>(loc, conf, anchors, maxv, denom, out);
  } else {
    k_main<false><<<NB * NC, 256, 0, stream>>>(loc, conf, anchors, nullptr, nullptr, out);
  }
}

// Round 4
// 433.408 us; speedup vs baseline: 1.3593x; 1.2436x over previous
//
#include <hip/hip_runtime.h>
#include <math.h>

#pragma clang fp contract(off)

#define NB 128
#define NA 8732
#define NC 21
#define TOPK 200
#define BCAP 512
#define CONF_T 0.01
#define NMS_T 0.045
#define NQ (NA / 4)   // 2183 float4 per class row (8732 % 4 == 0)
#define HSIZE 2048    // coarse buckets over f32 key bits [30:15]

// ---------------------------------------------------------------------------
// exact f64 masked softmax score (the f32 keys in ws are, up to ~2 f64-ulps,
// a monotone coarsening of this; all selection boundaries are resolved here)
// ---------------------------------------------------------------------------
__device__ __forceinline__ double exact_score(const float* __restrict__ conf,
                                              const float* __restrict__ maxv,
                                              const double* __restrict__ denom,
                                              int b, int i, int c) {
  size_t gi = (size_t)b * NA + i;
  double s = exp((double)conf[gi * NC + c] - (double)maxv[gi]) / denom[gi];
  return (s > CONF_T) ? s : 0.0;
}

__device__ __forceinline__ bool entBefore(double sa, int ia, double sb, int ib) {
  return (sa > sb) || (sa == sb && ia < ib);
}

// coarse bucket of an f32 score key; -1 = zero key (never selectable)
__device__ __forceinline__ int kbucket(unsigned key) {
  if (key == 0u) return -1;
  int x = (int)(key >> 15) - 0x7800;  // keys in (0.01,1] -> [0x47, 0x700]
  if (x < 1) x = 1;
  if (x > HSIZE - 1) x = HSIZE - 1;
  return x;
}

// ---------------------------------------------------------------------------
// k_prep: LDS-staged coalesced softmax. 21 f64 exps + 1 f64 div per anchor;
// writes f32 masked keys transposed [b][c-1][i] + maxv/denom for exactness.
// ---------------------------------------------------------------------------
__global__ __launch_bounds__(256) void k_prep(const float* __restrict__ conf,
                                              float* __restrict__ scores,
                                              float* __restrict__ maxv,
                                              double* __restrict__ denom) {
  __shared__ float rows[256 * NC];
  int base = blockIdx.x * 256;                    // NB*NA = 4366*256 exactly
  const float4* src = (const float4*)(conf + (size_t)base * NC);
  float4* dst = (float4*)rows;
  for (int t = threadIdx.x; t < (256 * NC) / 4; t += 256) dst[t] = src[t];
  __syncthreads();
  int g = base + threadIdx.x;
  const float* row = rows + threadIdx.x * NC;     // stride 21: conflict-free
  float v[NC];
#pragma unroll
  for (int k = 0; k < NC; ++k) v[k] = row[k];
  float mx = v[0];
#pragma unroll
  for (int k = 1; k < NC; ++k) mx = fmaxf(mx, v[k]);
  double e[NC], s = 0.0;
#pragma unroll
  for (int k = 0; k < NC; ++k) {
    e[k] = exp((double)v[k] - (double)mx);
    s += e[k];
  }
  maxv[g] = mx;
  denom[g] = s;
  double inv = 1.0 / s;
  int b = g / NA, i = g - b * NA;
#pragma unroll
  for (int cc = 1; cc < NC; ++cc) {
    double sc = e[cc] * inv;  // ~2ulp from e/s: boundaries resolved exactly later
    float key = (sc > CONF_T) ? (float)sc : 0.0f;
    scores[(size_t)(b * (NC - 1) + (cc - 1)) * NA + i] = key;
  }
}

// ---------------------------------------------------------------------------
// k_fast: one 256-thread block per (b,c), XCD-swizzled, 8 blocks/CU.
// ---------------------------------------------------------------------------
__global__ __launch_bounds__(256, 8) void k_fast(const float* __restrict__ loc,
                                                 const float* __restrict__ conf,
                                                 const float* __restrict__ anchors,
                                                 const float* __restrict__ scores,
                                                 const float* __restrict__ maxv,
                                                 const double* __restrict__ denom,
                                                 float* __restrict__ out) {
  int id = blockIdx.x;
  int xcd = id & 7, slot = id >> 3;        // same-b classes share an XCD
  int c = slot % NC;
  int b = (slot / NC) * 8 + xcd;
  int tid = threadIdx.x;
  float* outbase = out + ((size_t)(b * NC + c)) * TOPK * 5;

  if (c == 0) {
    for (int k = tid; k < TOPK * 5; k += 256) outbase[k] = 0.0f;
    return;
  }

  union U1 {  // radix phase vs box phase (disjoint in time)
    struct { unsigned hist[HSIZE]; unsigned chunk[256]; } r;
    struct { double dbox[TOPK][4]; double darea[TOPK]; } d;
  };
  union U2 {  // boundary phase vs suppression phase (disjoint in time)
    struct { double bnds[BCAP]; int bndi[BCAP]; } bb;
    unsigned supp[TOPK][8];  // word 7 = zero padding
  };
  __shared__ U1 u1;
  __shared__ U2 u2;
  __shared__ double ssel[256];
  __shared__ int isel[256];
  __shared__ unsigned keepw[7];
  __shared__ int ctl_cnt, ctl_m, ctl_n1, ctl_kneed, ctl_sparse, ctl_D;
  __shared__ int ctl_k;
  __shared__ unsigned ctl_pref;

  const float4* sc4 =
      (const float4*)(scores + (size_t)(b * (NC - 1) + (c - 1)) * NA);

  // ---- single-pass coarse histogram (zeros skipped, 4-key dedupe) ----
  for (int t = tid; t < HSIZE; t += 256) u1.r.hist[t] = 0u;
  if (tid == 0) { ctl_cnt = 0; ctl_m = 0; }
  __syncthreads();
  for (int q = tid; q < NQ; q += 256) {
    float4 k4 = sc4[q];
    unsigned kb[4] = {__float_as_uint(k4.x), __float_as_uint(k4.y),
                      __float_as_uint(k4.z), __float_as_uint(k4.w)};
    int bid[4];
    unsigned cw[4] = {1u, 1u, 1u, 1u};
#pragma unroll
    for (int t = 0; t < 4; ++t) bid[t] = kbucket(kb[t]);
#pragma unroll
    for (int a = 1; a < 4; ++a) {
#pragma unroll
      for (int b2 = 0; b2 < a; ++b2) {
        if (bid[a] >= 0 && bid[a] == bid[b2]) {
          cw[b2] += cw[a];
          bid[a] = -1;
          break;
        }
      }
    }
#pragma unroll
    for (int t = 0; t < 4; ++t)
      if (bid[t] >= 0) atomicAdd(&u1.r.hist[bid[t]], cw[t]);
  }
  __syncthreads();

  // ---- find boundary bucket D (suffix counts from the top) ----
  {
    unsigned csum = 0;
#pragma unroll
    for (int j = 0; j < 8; ++j) csum += u1.r.hist[tid * 8 + j];
    u1.r.chunk[tid] = csum;
  }
  __syncthreads();
  if (tid == 0) {
    unsigned cum = 0;
    int tc = -1;
    for (int t = 255; t >= 0; --t) {
      unsigned h = u1.r.chunk[t];
      if (cum + h >= (unsigned)TOPK) { tc = t; break; }
      cum += h;
    }
    if (tc < 0) {  // fewer than 200 positive keys
      ctl_sparse = 1; ctl_D = 0; ctl_n1 = (int)cum; ctl_kneed = TOPK - (int)cum;
    } else {
      int D = tc * 8;
      for (int j = 7; j >= 0; --j) {
        unsigned h = u1.r.hist[tc * 8 + j];
        if (cum + h >= (unsigned)TOPK) { D = tc * 8 + j; break; }
        cum += h;
      }
      ctl_sparse = 0; ctl_D = D; ctl_n1 = (int)cum; ctl_kneed = TOPK - (int)cum;
    }
  }
  __syncthreads();
  int sparse = ctl_sparse, D = ctl_D, n1 = ctl_n1, kneed = ctl_kneed;

  // ---- collect: buckets > D certain; bucket == D boundary ----
  for (int q = tid; q < NQ; q += 256) {
    float4 k4 = sc4[q];
    unsigned kb[4] = {__float_as_uint(k4.x), __float_as_uint(k4.y),
                      __float_as_uint(k4.z), __float_as_uint(k4.w)};
#pragma unroll
    for (int t = 0; t < 4; ++t) {
      int idx = kbucket(kb[t]);
      if (idx < 0) continue;
      if (idx > D) {
        int p = atomicAdd(&ctl_cnt, 1);
        if (p < 256) isel[p] = q * 4 + t;      // exactly n1 <= 199 entries
      } else if (!sparse && idx == D) {
        int p = atomicAdd(&ctl_m, 1);
        if (p < BCAP) u2.bb.bndi[p] = q * 4 + t;
      }
    }
  }
  __syncthreads();
  int m = sparse ? 0 : ctl_m;

  // ---- overflow fallback: exact 4-pass f32-key radix (R3-proven; ~never) ----
  if (!sparse && m > BCAP) {
    if (tid == 0) { ctl_k = TOPK; ctl_pref = 0u; }
    __syncthreads();
    for (int shift = 24; shift >= 0; shift -= 8) {
      u1.r.hist[tid] = 0u;
      __syncthreads();
      unsigned pref = ctl_pref;
      for (int q = tid; q < NQ; q += 256) {
        float4 k4 = sc4[q];
        unsigned kb[4] = {__float_as_uint(k4.x), __float_as_uint(k4.y),
                          __float_as_uint(k4.z), __float_as_uint(k4.w)};
#pragma unroll
        for (int t = 0; t < 4; ++t) {
          unsigned key = kb[t];
          if (key == 0u) continue;
          bool match = (shift == 24) || ((key >> (shift + 8)) == (pref >> (shift + 8)));
          if (match) atomicAdd(&u1.r.hist[(key >> shift) & 255u], 1u);
        }
      }
      __syncthreads();
      if (tid == 0) {
        int k = ctl_k;
        unsigned cum = 0;
        int d = 255;
        for (; d > 0; --d) {
          unsigned h = u1.r.hist[d];
          if (cum + h >= (unsigned)k) break;
          cum += h;
        }
        ctl_k = k - (int)cum;
        ctl_pref = pref | ((unsigned)d << shift);
      }
      __syncthreads();
    }
    unsigned Tf = ctl_pref;
    kneed = ctl_k;
    n1 = TOPK - kneed;
    if (tid == 0) { ctl_cnt = 0; ctl_m = 0; }
    __syncthreads();
    for (int q = tid; q < NQ; q += 256) {
      float4 k4 = sc4[q];
      unsigned kb[4] = {__float_as_uint(k4.x), __float_as_uint(k4.y),
                        __float_as_uint(k4.z), __float_as_uint(k4.w)};
#pragma unroll
      for (int t = 0; t < 4; ++t) {
        unsigned key = kb[t];
        if (key > Tf) {
          int p = atomicAdd(&ctl_cnt, 1);
          if (p < 256) isel[p] = q * 4 + t;
        } else if (key == Tf) {
          int p = atomicAdd(&ctl_m, 1);
          if (p < BCAP) u2.bb.bndi[p] = q * 4 + t;
        }
      }
    }
    __syncthreads();
    m = ctl_m;
    if (m > BCAP) m = BCAP;
  }

  // ---- boundary: exact f64 (score desc, index asc) ranking ----
  if (!sparse) {
    for (int q = tid; q < m; q += 256)
      u2.bb.bnds[q] = exact_score(conf, maxv, denom, b, u2.bb.bndi[q], c);
    __syncthreads();
    for (int q = tid; q < m; q += 256) {
      double sq = u2.bb.bnds[q];
      int iq = u2.bb.bndi[q];
      int rank = 0;
      for (int r = 0; r < m; ++r)
        if (entBefore(u2.bb.bnds[r], u2.bb.bndi[r], sq, iq)) ++rank;
      if (rank < kneed) isel[n1 + rank] = iq;
    }
  } else {
    // zero-score dummies: keep=false downstream -> zero output rows
    for (int j = n1 + tid; j < TOPK; j += 256) isel[j] = j - n1;
  }
  __syncthreads();
  int zf = sparse ? n1 : TOPK;

  // ---- exact f64 scores + sort sentinels ----
  if (tid < TOPK) {
    ssel[tid] = (tid < zf) ? exact_score(conf, maxv, denom, b, isel[tid], c) : 0.0;
  } else {
    ssel[tid] = -1.0;
    isel[tid] = 0x7fffffff;
  }

  // ---- bitonic sort 256: (score desc, index asc) ----
  for (int kk = 2; kk <= 256; kk <<= 1) {
    for (int j = kk >> 1; j > 0; j >>= 1) {
      __syncthreads();
      int ixj = tid ^ j;
      if (ixj > tid) {
        double s1 = ssel[tid], s2 = ssel[ixj];
        int i1 = isel[tid], i2 = isel[ixj];
        bool up = ((tid & kk) == 0);
        bool sw = up ? entBefore(s2, i2, s1, i1) : entBefore(s1, i1, s2, i2);
        if (sw) {
          ssel[tid] = s2; ssel[ixj] = s1;
          isel[tid] = i2; isel[ixj] = i1;
        }
      }
    }
  }
  __syncthreads();

  // ---- decode boxes in f64 (overwrites dead hist region) ----
  if (tid < TOPK) {
    int ai = isel[tid];
    const float* lp = loc + ((size_t)b * NA + ai) * 4;
    const float* ap = anchors + (size_t)ai * 4;
    double l0 = (double)lp[0], l1 = (double)lp[1];
    double l2 = (double)lp[2], l3 = (double)lp[3];
    double a0 = (double)ap[0], a1 = (double)ap[1];
    double a2 = (double)ap[2], a3 = (double)ap[3];
    double cx = a0 + (l0 * 0.1) * a2;
    double cy = a1 + (l1 * 0.1) * a3;
    double w = a2 * exp(l2 * 0.2);
    double h = a3 * exp(l3 * 0.2);
    double x1 = cx - 0.5 * w, y1 = cy - 0.5 * h;
    double x2 = cx + 0.5 * w, y2 = cy + 0.5 * h;
    u1.d.dbox[tid][0] = x1; u1.d.dbox[tid][1] = y1;
    u1.d.dbox[tid][2] = x2; u1.d.dbox[tid][3] = y2;
    u1.d.darea[tid] = (x2 - x1) * (y2 - y1);
  }
  __syncthreads();

  // ---- suppression bitmask: f64 multiply-compare (no divide) ----
  for (int T = tid; T < TOPK * 7; T += 256) {
    int i = T / 7, w = T - i * 7;
    double ax1 = u1.d.dbox[i][0], ay1 = u1.d.dbox[i][1];
    double ax2 = u1.d.dbox[i][2], ay2 = u1.d.dbox[i][3];
    double aar = u1.d.darea[i];
    unsigned bits = 0u;
    int j0 = w * 32;
    int j1 = j0 + 32;
    if (j1 > TOPK) j1 = TOPK;
    int js = (j0 > i + 1) ? j0 : i + 1;
    for (int j = js; j < j1; ++j) {
      double lx = fmax(ax1, u1.d.dbox[j][0]);
      double ly = fmax(ay1, u1.d.dbox[j][1]);
      double rx = fmin(ax2, u1.d.dbox[j][2]);
      double ry = fmin(ay2, u1.d.dbox[j][3]);
      double iw = rx - lx; if (iw < 0.0) iw = 0.0;
      double ih = ry - ly; if (ih < 0.0) ih = 0.0;
      double inter = iw * ih;
      double uni = aar + u1.d.darea[j] - inter + 1e-12;
      if (inter > NMS_T * uni) bits |= 1u << (j - j0);  // == iou > T (2ulp)
    }
    u2.supp[i][w] = bits;
  }
  for (int i2 = tid; i2 < TOPK; i2 += 256) u2.supp[i2][7] = 0u;
  __syncthreads();

  // ---- greedy NMS on wave 0: keep bits in registers, next-row prefetch ----
  if (tid < 64) {
    int l = tid;
    unsigned kr = 0u;
#pragma unroll
    for (int q = 0; q < 4; ++q) {
      int j = l + 64 * q;
      if (j < TOPK && ssel[j] > CONF_T) kr |= 1u << q;
    }
    int base = l >> 5;  // 0 or 1
    unsigned r0 = u2.supp[0][base], r1 = u2.supp[0][base + 2];
    unsigned r2 = u2.supp[0][base + 4], r3 = u2.supp[0][base + 6];
    for (int i = 0; i < TOPK; ++i) {
      int ip = (i + 1 < TOPK) ? i + 1 : i;
      unsigned n0 = u2.supp[ip][base], n1w = u2.supp[ip][base + 2];
      unsigned n2 = u2.supp[ip][base + 4], n3 = u2.supp[ip][base + 6];
      unsigned krow = (unsigned)__shfl((int)kr, i & 63);
      if ((krow >> (i >> 6)) & 1u) {
        unsigned bm = 1u << (l & 31);
        if (r0 & bm) kr &= ~1u;
        if (r1 & bm) kr &= ~2u;
        if (r2 & bm) kr &= ~4u;
        if (r3 & bm) kr &= ~8u;
      }
      r0 = n0; r1 = n1w; r2 = n2; r3 = n3;
    }
#pragma unroll
    for (int q = 0; q < 4; ++q) {
      unsigned long long bal = __ballot((int)((kr >> q) & 1u));
      if (l == 0) {
        keepw[2 * q] = (unsigned)bal;
        if (2 * q + 1 < 7) keepw[2 * q + 1] = (unsigned)(bal >> 32);
      }
    }
  }
  __syncthreads();

  // ---- pack kept rows to the front, zero-fill the rest ----
  int nk = 0;
#pragma unroll
  for (int w = 0; w < 7; ++w) nk += __popc(keepw[w]);
  if (tid < TOPK) {
    int j = tid;
    bool kept = (keepw[j >> 5] >> (j & 31)) & 1u;
    if (kept) {
      int pos = 0;
      for (int w = 0; w < (j >> 5); ++w) pos += __popc(keepw[w]);
      pos += __popc(keepw[j >> 5] & ((1u << (j & 31)) - 1u));
      float* o = outbase + (size_t)pos * 5;
      o[0] = (float)ssel[j];
      o[1] = (float)u1.d.dbox[j][0];
      o[2] = (float)u1.d.dbox[j][1];
      o[3] = (float)u1.d.dbox[j][2];
      o[4] = (float)u1.d.dbox[j][3];
    }
    if (j >= nk) {
      float* o = outbase + (size_t)j * 5;
      o[0] = 0.0f; o[1] = 0.0f; o[2] = 0.0f; o[3] = 0.0f; o[4] = 0.0f;
    }
  }
}

// ===========================================================================
// Small-workspace fallback (R2-proven) — only if ws can't hold the score keys
// ===========================================================================
template <bool USE_WS>
__device__ __forceinline__ double score_masked(const float* __restrict__ conf,
                                               const float* __restrict__ maxv,
                                               const double* __restrict__ denom,
                                               int b, int i, int c) {
  size_t gi = (size_t)b * NA + i;
  double s;
  if (USE_WS) {
    s = exp((double)conf[gi * NC + c] - (double)maxv[gi]) / denom[gi];
  } else {
    const float* row = conf + gi * NC;
    float mx = row[0];
    for (int k = 1; k < NC; ++k) mx = fmaxf(mx, row[k]);
    double d = 0.0;
    for (int k = 0; k < NC; ++k) d += exp((double)row[k] - (double)mx);
    s = exp((double)row[c] - (double)mx) / d;
  }
  return (s > CONF_T) ? s : 0.0;
}

__global__ void k_pre(const float* __restrict__ conf, float* __restrict__ maxv,
                      double* __restrict__ denom) {
  int g = blockIdx.x * blockDim.x + threadIdx.x;
  if (g >= NB * NA) return;
  const float* row = conf + (size_t)g * NC;
  float mx = row[0];
  for (int c = 1; c < NC; ++c) mx = fmaxf(mx, row[c]);
  double s = 0.0;
  for (int c = 0; c < NC; ++c) s += exp((double)row[c] - (double)mx);
  maxv[g] = mx;
  denom[g] = s;
}

template <bool USE_WS>
__global__ __launch_bounds__(256) void k_main(const float* __restrict__ loc,
                                              const float* __restrict__ conf,
                                              const float* __restrict__ anchors,
                                              const float* __restrict__ maxv,
                                              const double* __restrict__ denom,
                                              float* __restrict__ out) {
  int bc = blockIdx.x;
  int b = bc / NC;
  int c = bc % NC;
  int tid = threadIdx.x;
  float* outbase = out + (size_t)bc * TOPK * 5;
  if (c == 0) {
    for (int k = tid; k < TOPK * 5; k += 256) outbase[k] = 0.0f;
    return;
  }
  union U {
    float sf[NA];
    struct { double box[TOPK][4]; double area[TOPK]; } p2;
  };
  __shared__ U u;
  __shared__ double ssel[256];
  __shared__ int isel[256];
  __shared__ unsigned hist[256];
  __shared__ double bnds[256];
  __shared__ int bndi[256];
  __shared__ int keepL[256];
  __shared__ unsigned long long wmask[4];
  __shared__ int ctl_k, ctl_cnt, ctl_m;
  __shared__ unsigned ctl_pref;

  for (int i = tid; i < NA; i += 256)
    u.sf[i] = (float)score_masked<USE_WS>(conf, maxv, denom, b, i, c);
  if (tid == 0) { ctl_k = TOPK; ctl_pref = 0u; }
  __syncthreads();
  for (int shift = 24; shift >= 0; shift -= 8) {
    hist[tid] = 0u;
    __syncthreads();
    unsigned pref = ctl_pref;
    for (int i = tid; i < NA; i += 256) {
      unsigned key = __float_as_uint(u.sf[i]);
      bool match = (shift == 24) || ((key >> (shift + 8)) == (pref >> (shift + 8)));
      if (match) atomicAdd(&hist[(key >> shift) & 255u], 1u);
    }
    __syncthreads();
    if (tid == 0) {
      int k = ctl_k;
      unsigned cum = 0;
      int d = 255;
      for (; d > 0; --d) {
        unsigned h = hist[d];
        if (cum + h >= (unsigned)k) break;
        cum += h;
      }
      ctl_k = k - (int)cum;
      ctl_pref = pref | ((unsigned)d << shift);
    }
    __syncthreads();
  }
  unsigned Tf = ctl_pref;
  int kneed = ctl_k;
  int n1 = TOPK - kneed;
  if (tid == 0) { ctl_cnt = 0; ctl_m = 0; }
  __syncthreads();
  for (int i = tid; i < NA; i += 256) {
    unsigned key = __float_as_uint(u.sf[i]);
    if (key > Tf) {
      int p = atomicAdd(&ctl_cnt, 1);
      if (p < 256) isel[p] = i;
    } else if (key == Tf && Tf != 0u) {
      int q = atomicAdd(&ctl_m, 1);
      if (q < 256) bndi[q] = i;
    }
  }
  __syncthreads();
  int zf;
  if (Tf == 0u) {
    zf = n1;
    for (int j = n1 + tid; j < TOPK; j += 256) isel[j] = j - n1;
  } else {
    zf = TOPK;
    int m = ctl_m;
    if (m > 256) m = 256;
    if (tid < m) bnds[tid] = score_masked<USE_WS>(conf, maxv, denom, b, bndi[tid], c);
    __syncthreads();
    if (tid < m) {
      double sq = bnds[tid];
      int iq = bndi[tid];
      int rank = 0;
      for (int r = 0; r < m; ++r)
        if (entBefore(bnds[r], bndi[r], sq, iq)) ++rank;
      if (rank < kneed) isel[n1 + rank] = iq;
    }
  }
  __syncthreads();
  if (tid < TOPK) {
    ssel[tid] = (tid < zf) ? score_masked<USE_WS>(conf, maxv, denom, b, isel[tid], c) : 0.0;
  } else {
    ssel[tid] = -1.0;
    isel[tid] = 0x7fffffff;
  }
  for (int kk = 2; kk <= 256; kk <<= 1) {
    for (int j = kk >> 1; j > 0; j >>= 1) {
      __syncthreads();
      int ixj = tid ^ j;
      if (ixj > tid) {
        double s1 = ssel[tid], s2 = ssel[ixj];
        int i1 = isel[tid], i2 = isel[ixj];
        bool up = ((tid & kk) == 0);
        bool sw = up ? entBefore(s2, i2, s1, i1) : entBefore(s1, i1, s2, i2);
        if (sw) {
          ssel[tid] = s2; ssel[ixj] = s1;
          isel[tid] = i2; isel[ixj] = i1;
        }
      }
    }
  }
  __syncthreads();
  if (tid < TOPK) {
    int ai = isel[tid];
    const float* lp = loc + ((size_t)b * NA + ai) * 4;
    const float* ap = anchors + (size_t)ai * 4;
    double l0 = (double)lp[0], l1 = (double)lp[1];
    double l2 = (double)lp[2], l3 = (double)lp[3];
    double a0 = (double)ap[0], a1 = (double)ap[1];
    double a2 = (double)ap[2], a3 = (double)ap[3];
    double cx = a0 + (l0 * 0.1) * a2;
    double cy = a1 + (l1 * 0.1) * a3;
    double w = a2 * exp(l2 * 0.2);
    double h = a3 * exp(l3 * 0.2);
    u.p2.box[tid][0] = cx - 0.5 * w;
    u.p2.box[tid][1] = cy - 0.5 * h;
    u.p2.box[tid][2] = cx + 0.5 * w;
    u.p2.box[tid][3] = cy + 0.5 * h;
    u.p2.area[tid] = w * h;
  }
  __syncthreads();
  double mx1 = 0, my1 = 0, mx2 = 0, my2 = 0, mar = 0;
  if (tid < TOPK) {
    mx1 = u.p2.box[tid][0]; my1 = u.p2.box[tid][1];
    mx2 = u.p2.box[tid][2]; my2 = u.p2.box[tid][3];
    mar = u.p2.area[tid];
  }
  keepL[tid] = (tid < TOPK) && (ssel[tid] > CONF_T);
  __syncthreads();
  for (int i = 0; i < TOPK; ++i) {
    int ki = keepL[i];
    if (ki && tid > i && tid < TOPK && keepL[tid]) {
      double lx = fmax(u.p2.box[i][0], mx1);
      double ly = fmax(u.p2.box[i][1], my1);
      double rx = fmin(u.p2.box[i][2], mx2);
      double ry = fmin(u.p2.box[i][3], my2);
      double iw = rx - lx; if (iw < 0.0) iw = 0.0;
      double ih = ry - ly; if (ih < 0.0) ih = 0.0;
      double inter = iw * ih;
      double iou = inter / (u.p2.area[i] + mar - inter + 1e-12);
      if (iou > NMS_T) keepL[tid] = 0;
    }
    __syncthreads();
  }
  bool kj = (tid < TOPK) && (keepL[tid] != 0);
  unsigned long long bal = __ballot((int)kj);
  int wave = tid >> 6, lane = tid & 63;
  if (lane == 0) wmask[wave] = bal;
  __syncthreads();
  int nk = 0;
#pragma unroll
  for (int w = 0; w < 4; ++w) nk += __popcll(wmask[w]);
  if (kj) {
    int pos = 0;
    for (int w = 0; w < wave; ++w) pos += __popcll(wmask[w]);
    pos += __popcll(bal & ((1ull << lane) - 1ull));
    float* o = outbase + (size_t)pos * 5;
    o[0] = (float)ssel[tid];
    o[1] = (float)u.p2.box[tid][0];
    o[2] = (float)u.p2.box[tid][1];
    o[3] = (float)u.p2.box[tid][2];
    o[4] = (float)u.p2.box[tid][3];
  }
  if (tid < TOPK && tid >= nk) {
    float* o = outbase + (size_t)tid * 5;
    o[0] = 0.0f; o[1] = 0.0f; o[2] = 0.0f; o[3] = 0.0f; o[4] = 0.0f;
  }
}

// ---------------------------------------------------------------------------
extern "C" void kernel_launch(void* const* d_in, const int* in_sizes, int n_in,
                              void* d_out, int out_size, void* d_ws, size_t ws_size,
                              hipStream_t stream) {
  const float* loc = (const float*)d_in[0];
  const float* conf = (const float*)d_in[1];
  const float* anchors = (const float*)d_in[2];
  float* out = (float*)d_out;

  const size_t scores_bytes = (size_t)NB * (NC - 1) * NA * sizeof(float);
  const size_t denom_off = scores_bytes;  // 8-byte aligned (scores_bytes % 8 == 0)
  const size_t maxv_off = denom_off + (size_t)NB * NA * sizeof(double);
  const size_t WS_FAST = maxv_off + (size_t)NB * NA * sizeof(float);
  const size_t WS_SMALL = (size_t)NB * NA * (sizeof(double) + sizeof(float));
  int total = NB * NA;

  if (ws_size >= WS_FAST) {
    float* scores = (float*)d_ws;
    double* denom = (double*)((char*)d_ws + denom_off);
    float* maxv = (float*)((char*)d_ws + maxv_off);
    k_prep<<<total / 256, 256, 0, stream>>>(conf, scores, maxv, denom);
    k_fast<<<NB * NC, 256, 0, stream>>>(loc, conf, anchors, scores, maxv, denom, out);
  } else if (ws_size >= WS_SMALL) {
    double* denom = (double*)d_ws;
    float* maxv = (float*)((char*)d_ws + (size_t)NB * NA * sizeof(double));
    k_pre<<<(total + 255) / 256, 256, 0, stream>>>(conf, maxv, denom);
    k_main<true><<<NB * NC, 256, 0, stream>>>(loc, conf, anchors, maxv, denom, out);
  } else {
    k_main<false><<<NB * NC, 256, 0, stream>>>(loc, conf, anchors, nullptr, nullptr, out);
  }
}